// Round 12
// baseline (395.349 us; speedup 1.0000x reference)
//
#include <hip/hip_runtime.h>
#include <hip/hip_bf16.h>
#include <math.h>

#define H   128
#define NR  6
#define NOUT 64

typedef __attribute__((ext_vector_type(8))) short short8;
typedef __attribute__((ext_vector_type(4))) float floatx4;

// swish with fast rcp: outputs feed bf16 (4e-3) or bf16-split (1.5e-5) paths;
// v_rcp_f32 (~1e-7 rel err) replaces the ~10-inst IEEE div sequence.
__device__ __forceinline__ float swishf(float z) {
  float t = __expf(-z);
  return z * __builtin_amdgcn_rcpf(1.0f + t);
}

__device__ __forceinline__ ushort f2bf(float x) {
  __hip_bfloat16 b = __float2bfloat16(x);
  return *reinterpret_cast<ushort*>(&b);
}

// fast RNE float->bf16 (no NaN handling; inputs are finite here)
__device__ __forceinline__ ushort f2bf_rne(float x) {
  unsigned int u = __float_as_uint(x);
  u += 0x7FFFu + ((u >> 16) & 1u);
  return (ushort)(u >> 16);
}

__device__ __forceinline__ float bf2f(ushort u) {
  unsigned int v = ((unsigned int)u) << 16;
  return __uint_as_float(v);
}

// async 16B global->LDS (wave-uniform LDS base + lane*16)
__device__ __forceinline__ void async_copy16(const void* g, void* l) {
  __builtin_amdgcn_global_load_lds(
      (const __attribute__((address_space(1))) unsigned int*)g,
      (__attribute__((address_space(3))) unsigned int*)l, 16, 0, 0);
}

// ---------------- fused init: zero nodeA + cnt, weight conversions ----------------
__global__ void k_init(float4* __restrict__ nodeA, int n4, int* __restrict__ cnt, int n,
                       const float* __restrict__ Wl, const float* __restrict__ Wx,
                       const float* __restrict__ Wls, const float* __restrict__ Wout,
                       ushort* __restrict__ Wlbf,
                       ushort* __restrict__ Wxhi, ushort* __restrict__ Wxlo,
                       ushort* __restrict__ Wlshi, ushort* __restrict__ Wlslo,
                       ushort* __restrict__ Wouthi, ushort* __restrict__ Woutlo) {
  int i = blockIdx.x * blockDim.x + threadIdx.x;
  if (i < n4) nodeA[i] = make_float4(0.f, 0.f, 0.f, 0.f);
  if (i < n) cnt[i] = 0;
  int idx = i;
  if (idx < 49152) {
    Wlbf[idx] = f2bf(Wl[idx]);
    return;
  }
  idx -= 49152;
  if (idx < 16384) {
    float x = Wx[idx];
    ushort h = f2bf(x);
    Wxhi[idx] = h; Wxlo[idx] = f2bf(x - bf2f(h));
    return;
  }
  idx -= 16384;
  if (idx < 49152) {
    float x = Wls[idx];
    ushort h = f2bf(x);
    Wlshi[idx] = h; Wlslo[idx] = f2bf(x - bf2f(h));
    return;
  }
  idx -= 49152;
  if (idx < 8192) {
    float x = Wout[idx];
    ushort h = f2bf(x);
    Wouthi[idx] = h; Woutlo[idx] = f2bf(x - bf2f(h));
  }
}

// ---------------- counting sort by dst: hist / scan ----------------
__global__ void k_hist(const int* __restrict__ dst, int* __restrict__ cnt, int E) {
  int i = blockIdx.x * blockDim.x + threadIdx.x;
  if (i < E) atomicAdd(&cnt[dst[i]], 1);
}

// tiled coalesced scan, 1 block: per-1024 tile {coalesced load (prefetched one
// tile ahead), wave shfl-scan, wave-sum scan, coalesced store}.
__global__ __launch_bounds__(1024) void k_scan(const int* __restrict__ cnt,
                                               int* __restrict__ cur, int N) {
  __shared__ int wsum[16];
  __shared__ int baseS;
  const int tid = threadIdx.x;
  const int lane = tid & 63, wv = tid >> 6;
  if (tid == 0) baseS = 0;
  __syncthreads();
  int vcur = (tid < N) ? cnt[tid] : 0;
  for (int t0 = 0; t0 < N; t0 += 1024) {
    int inext = t0 + 1024 + tid;
    int vnext = (inext < N) ? cnt[inext] : 0;   // prefetch next tile
    int orig = vcur;
    int v = vcur;
#pragma unroll
    for (int off = 1; off < 64; off <<= 1) {
      int t = __shfl_up(v, off, 64);
      if (lane >= off) v += t;
    }
    if (lane == 63) wsum[wv] = v;
    __syncthreads();
    if (wv == 0 && lane < 16) {
      int t = wsum[lane];
#pragma unroll
      for (int off = 1; off < 16; off <<= 1) {
        int u2 = __shfl_up(t, off, 64);
        if (lane >= off) t += u2;
      }
      wsum[lane] = t;  // inclusive wave sums
    }
    __syncthreads();
    int excl = baseS + (wv > 0 ? wsum[wv - 1] : 0) + (v - orig);
    int i = t0 + tid;
    if (i < N) cur[i] = excl;
    __syncthreads();               // all baseS/wsum reads done
    if (tid == 0) baseS += wsum[15];
    vcur = vnext;
    __syncthreads();               // baseS update visible; wsum free for reuse
  }
}

// ---------------- fused scatter + per-edge rbf + triplet angles ----------------
// For edge i: p = atomicAdd(cur[dst]) gives its sorted slot; write rbf/ssrc/sdst
// directly at p (no perm array, no extra E-pass).
__global__ __launch_bounds__(256) void k_scatter_feat_ang(
    const float* __restrict__ pos, const int* __restrict__ esrc,
    const int* __restrict__ edst, const float* __restrict__ freq,
    int* __restrict__ cur,
    float* __restrict__ rbfG,       // [E][6] sorted
    int* __restrict__ ssrc, int* __restrict__ sdst, int E, int EB,
    const int* __restrict__ ii, const int* __restrict__ jj, const int* __restrict__ kk,
    float* __restrict__ ang, int T) {
  if (blockIdx.x < (unsigned)EB) {
    int i = blockIdx.x * 256 + threadIdx.x;
    if (i >= E) return;
    const int s = esrc[i], d = edst[i];
    const int p = atomicAdd(&cur[d], 1);
    float dx = pos[d * 3 + 0] - pos[s * 3 + 0];
    float dy = pos[d * 3 + 1] - pos[s * 3 + 1];
    float dz = pos[d * 3 + 2] - pos[s * 3 + 2];
    float dist = sqrtf(dx * dx + dy * dy + dz * dz);
    float dn = dist * 0.2f;
    float inv = __builtin_amdgcn_rcpf(dn);   // feeds bf16-precision path; rcp ok
    float dn2 = dn * dn;
    float dp = dn2 * dn2 * dn;  // dn^5
    float env = inv - 21.0f * dp + 35.0f * dp * dn - 15.0f * dp * dn2;
#pragma unroll
    for (int r = 0; r < NR; ++r)
      rbfG[(size_t)p * NR + r] = env * __sinf(freq[r] * dn);  // fast sin: arg < 19 rad
    ssrc[p] = s;
    sdst[p] = d;
  } else {
    int t = (blockIdx.x - EB) * 256 + threadIdx.x;
    if (t >= T) return;
    int i = ii[t], j = jj[t], k = kk[t];
    float pix = pos[i * 3], piy = pos[i * 3 + 1], piz = pos[i * 3 + 2];
    float vjx = pos[j * 3] - pix, vjy = pos[j * 3 + 1] - piy, vjz = pos[j * 3 + 2] - piz;
    float vkx = pos[k * 3] - pix, vky = pos[k * 3 + 1] - piy, vkz = pos[k * 3 + 2] - piz;
    float a = vjx * vkx + vjy * vky + vjz * vkz;
    float cx = vjy * vkz - vjz * vky;
    float cy = vjz * vkx - vjx * vkz;
    float cz = vjx * vky - vjy * vkx;
    float b = sqrtf(cx * cx + cy * cy + cz * cz);
    ang[t] = atan2f(b, a);   // direct output: keep libm accuracy
  }
}

// ---------------- x @ Wx^T -> bf16, 128-row tiles, 512 threads ----------------
// Restructured like k_edge_mfma (proven): B staged once per 128 rows (half the
// per-row staging of the old 64-tile), half the blocks. LDS 32KB -> 32 waves/CU.
__global__ __launch_bounds__(512, 4) void k_x_gemm(
    const float* __restrict__ A,      // [M][128] fp32
    const ushort* __restrict__ Bhi,   // [128][128]
    const ushort* __restrict__ Blo,
    ushort* __restrict__ C,           // [M][128] bf16
    int M) {
  __shared__ alignas(16) ushort Ah[128 * 32];
  __shared__ alignas(16) ushort Al[128 * 32];
  __shared__ alignas(16) ushort Bh[128 * 32];
  __shared__ alignas(16) ushort Bl[128 * 32];

  const int tid = threadIdx.x;
  const int m0 = blockIdx.x * 128;
  const int w = tid >> 6, lane = tid & 63;
  const int l15 = lane & 15, quad = lane >> 4;
  const int wm = (w >> 1) * 32;   // 4 row strips over 128
  const int wn = (w & 1) * 64;    // 2 col halves

  floatx4 acc[2][4];
#pragma unroll
  for (int i = 0; i < 2; ++i)
#pragma unroll
    for (int j = 0; j < 4; ++j) acc[i][j] = floatx4{0.f, 0.f, 0.f, 0.f};

  for (int c = 0; c < 4; ++c) {
    const int kb = c * 32;
    {
      int row = tid >> 2, g = tid & 3;   // 128 rows x 4 K-groups
      int m = m0 + row;
      float4 v0 = make_float4(0.f, 0.f, 0.f, 0.f), v1 = v0;
      if (m < M) {
        v0 = *(const float4*)&A[(size_t)m * 128 + kb + g * 8];
        v1 = *(const float4*)&A[(size_t)m * 128 + kb + g * 8 + 4];
      }
      float xs[8] = {v0.x, v0.y, v0.z, v0.w, v1.x, v1.y, v1.z, v1.w};
      short8 hi, lo;
#pragma unroll
      for (int j = 0; j < 8; ++j) {
        ushort h = f2bf_rne(xs[j]);
        hi[j] = (short)h;
        lo[j] = (short)f2bf_rne(xs[j] - bf2f(h));
      }
      int slot = row * 4 + (g ^ ((row >> 1) & 3));
      *(short8*)(Ah + slot * 8) = hi;
      *(short8*)(Al + slot * 8) = lo;
    }
    {
      // B: 128 rows x 32 K = 512 16B-units, 8 waves x 1 issue
      int s = w * 64 + lane;
      int brow = s >> 2, gp = s & 3;
      int gg = gp ^ ((brow >> 1) & 3);
      int lb = __builtin_amdgcn_readfirstlane(w * 64);
      async_copy16((const void*)(Bhi + (size_t)brow * 128 + kb + gg * 8), (void*)(Bh + lb * 8));
      async_copy16((const void*)(Blo + (size_t)brow * 128 + kb + gg * 8), (void*)(Bl + lb * 8));
    }
    __syncthreads();
    short8 ah[2], al[2], bh[4], blv[4];
#pragma unroll
    for (int i = 0; i < 2; ++i) {
      int m = wm + i * 16 + l15;
      int slot = m * 4 + (quad ^ ((m >> 1) & 3));
      ah[i] = *(const short8*)(Ah + slot * 8);
      al[i] = *(const short8*)(Al + slot * 8);
    }
#pragma unroll
    for (int j = 0; j < 4; ++j) {
      int n = wn + j * 16 + l15;
      int slot = n * 4 + (quad ^ ((n >> 1) & 3));
      bh[j] = *(const short8*)(Bh + slot * 8);
      blv[j] = *(const short8*)(Bl + slot * 8);
    }
#pragma unroll
    for (int i = 0; i < 2; ++i)
#pragma unroll
      for (int j = 0; j < 4; ++j) {
        acc[i][j] = __builtin_amdgcn_mfma_f32_16x16x32_bf16(ah[i], bh[j], acc[i][j], 0, 0, 0);
        acc[i][j] = __builtin_amdgcn_mfma_f32_16x16x32_bf16(ah[i], blv[j], acc[i][j], 0, 0, 0);
        acc[i][j] = __builtin_amdgcn_mfma_f32_16x16x32_bf16(al[i], bh[j], acc[i][j], 0, 0, 0);
      }
    __syncthreads();
  }

#pragma unroll
  for (int i = 0; i < 2; ++i)
#pragma unroll
    for (int r = 0; r < 4; ++r) {
      int m = m0 + wm + i * 16 + quad * 4 + r;
      if (m < M) {
#pragma unroll
        for (int j = 0; j < 4; ++j) {
          int n = wn + j * 16 + l15;
          C[(size_t)m * 128 + n] = f2bf_rne(acc[i][j][r]);
        }
      }
    }
}

// ---------------- fused node MLP: 3x (swish o Wls) + Wout, 512 threads ----------
// 64-row tile (LDS-bound at 51KB), 8 waves as 2x4 quadrants (32r x 32c each);
// half the per-wave serial MFMA chain between barriers vs the 256-thread form,
// 16 waves/CU (vs 12). Out layer: 32r x 16c per wave.
__global__ __launch_bounds__(512, 4) void k_node_mlp(
    const float* __restrict__ nodeA,   // [M][128]
    const ushort* __restrict__ Wlshi,  // [3][128][128]
    const ushort* __restrict__ Wlslo,
    const ushort* __restrict__ Wouthi, // [64][128]
    const ushort* __restrict__ Woutlo,
    const float* __restrict__ bls,     // [3][128]
    float* __restrict__ P,             // [M][64]
    int M) {
  __shared__ alignas(16) ushort AactH[64 * 16 * 8];
  __shared__ alignas(16) ushort AactL[64 * 16 * 8];
  __shared__ alignas(16) ushort Bh[128 * 4 * 8];
  __shared__ alignas(16) ushort Bl[128 * 4 * 8];
  __shared__ float blsS[3 * 128];

  const int tid = threadIdx.x;
  const int m0 = blockIdx.x * 64;
  const int w = tid >> 6, lane = tid & 63;
  const int l15 = lane & 15, quad = lane >> 4;
  const int wm = (w >> 2) * 32;   // 2 row strips over 64
  const int wn = (w & 3) * 32;    // 4 col strips over 128

  for (int i = tid; i < 3 * 128; i += 512) blsS[i] = bls[i];

  floatx4 acc[2][2];

  for (int p = 0; p < 3; ++p) {
    const ushort* Bhg = Wlshi + p * 128 * 128;
    const ushort* Blg = Wlslo + p * 128 * 128;
#pragma unroll
    for (int i = 0; i < 2; ++i)
#pragma unroll
      for (int j = 0; j < 2; ++j) acc[i][j] = floatx4{0.f, 0.f, 0.f, 0.f};

    for (int c = 0; c < 4; ++c) {
      const int kb = c * 32;
      {
        // B: 128 rows x 32 K = 512 units, 8 waves x 1 issue
        int s = w * 64 + lane;
        int brow = s >> 2, gp = s & 3;
        int gg = gp ^ ((brow >> 1) & 3);
        int lb = __builtin_amdgcn_readfirstlane(w * 64);
        async_copy16((const void*)(Bhg + (size_t)brow * 128 + kb + gg * 8), (void*)(Bh + lb * 8));
        async_copy16((const void*)(Blg + (size_t)brow * 128 + kb + gg * 8), (void*)(Bl + lb * 8));
      }
      __syncthreads();
      short8 ah[2], al[2];
      if (p == 0) {
#pragma unroll
        for (int i = 0; i < 2; ++i) {
          int m = m0 + wm + i * 16 + l15;
          float4 v0 = make_float4(0.f, 0.f, 0.f, 0.f), v1 = v0;
          if (m < M) {
            v0 = *(const float4*)&nodeA[(size_t)m * 128 + kb + quad * 8];
            v1 = *(const float4*)&nodeA[(size_t)m * 128 + kb + quad * 8 + 4];
          }
          float xs[8] = {v0.x, v0.y, v0.z, v0.w, v1.x, v1.y, v1.z, v1.w};
#pragma unroll
          for (int j = 0; j < 8; ++j) {
            ushort hh = f2bf_rne(xs[j]);
            ah[i][j] = (short)hh;
            al[i][j] = (short)f2bf_rne(xs[j] - bf2f(hh));
          }
        }
      } else {
#pragma unroll
        for (int i = 0; i < 2; ++i) {
          int arow = wm + i * 16 + l15;
          int g16 = c * 4 + quad;
          int slot = arow * 16 + (g16 ^ (arow & 15));
          ah[i] = *(const short8*)(AactH + slot * 8);
          al[i] = *(const short8*)(AactL + slot * 8);
        }
      }
      short8 bh[2], blv[2];
#pragma unroll
      for (int j = 0; j < 2; ++j) {
        int n = wn + j * 16 + l15;
        int slot = n * 4 + (quad ^ ((n >> 1) & 3));
        bh[j] = *(const short8*)(Bh + slot * 8);
        blv[j] = *(const short8*)(Bl + slot * 8);
      }
#pragma unroll
      for (int i = 0; i < 2; ++i)
#pragma unroll
        for (int j = 0; j < 2; ++j) {
          acc[i][j] = __builtin_amdgcn_mfma_f32_16x16x32_bf16(ah[i], bh[j], acc[i][j], 0, 0, 0);
          acc[i][j] = __builtin_amdgcn_mfma_f32_16x16x32_bf16(ah[i], blv[j], acc[i][j], 0, 0, 0);
          acc[i][j] = __builtin_amdgcn_mfma_f32_16x16x32_bf16(al[i], bh[j], acc[i][j], 0, 0, 0);
        }
      __syncthreads();
    }
#pragma unroll
    for (int i = 0; i < 2; ++i)
#pragma unroll
      for (int r = 0; r < 4; ++r) {
        int row = wm + i * 16 + quad * 4 + r;
#pragma unroll
        for (int j = 0; j < 2; ++j) {
          int col = wn + j * 16 + l15;
          float z = acc[i][j][r] + blsS[p * 128 + col];
          z = swishf(z);
          ushort hh = f2bf_rne(z);
          int slot = row * 16 + ((col >> 3) ^ (row & 15));
          AactH[slot * 8 + (col & 7)] = hh;
          AactL[slot * 8 + (col & 7)] = f2bf_rne(z - bf2f(hh));
        }
      }
    __syncthreads();
  }

  const int wn3 = (w & 3) * 16;   // 4 col strips of 16 over 64
#pragma unroll
  for (int i = 0; i < 2; ++i) acc[i][0] = floatx4{0.f, 0.f, 0.f, 0.f};

  for (int c = 0; c < 4; ++c) {
    const int kb = c * 32;
    if (w < 4) {
      // Wout: 64 rows x 32 K = 256 units, waves 0-3 x 1 issue
      int s = w * 64 + lane;
      int brow = s >> 2, gp = s & 3;
      int gg = gp ^ ((brow >> 1) & 3);
      int lb = __builtin_amdgcn_readfirstlane(w * 64);
      async_copy16((const void*)(Wouthi + (size_t)brow * 128 + kb + gg * 8), (void*)(Bh + lb * 8));
      async_copy16((const void*)(Woutlo + (size_t)brow * 128 + kb + gg * 8), (void*)(Bl + lb * 8));
    }
    __syncthreads();
    short8 ah[2], al[2], bh, blv;
#pragma unroll
    for (int i = 0; i < 2; ++i) {
      int arow = wm + i * 16 + l15;
      int g16 = c * 4 + quad;
      int slot = arow * 16 + (g16 ^ (arow & 15));
      ah[i] = *(const short8*)(AactH + slot * 8);
      al[i] = *(const short8*)(AactL + slot * 8);
    }
    {
      int n = wn3 + l15;
      int slot = n * 4 + (quad ^ ((n >> 1) & 3));
      bh = *(const short8*)(Bh + slot * 8);
      blv = *(const short8*)(Bl + slot * 8);
    }
#pragma unroll
    for (int i = 0; i < 2; ++i) {
      acc[i][0] = __builtin_amdgcn_mfma_f32_16x16x32_bf16(ah[i], bh, acc[i][0], 0, 0, 0);
      acc[i][0] = __builtin_amdgcn_mfma_f32_16x16x32_bf16(ah[i], blv, acc[i][0], 0, 0, 0);
      acc[i][0] = __builtin_amdgcn_mfma_f32_16x16x32_bf16(al[i], bh, acc[i][0], 0, 0, 0);
    }
    __syncthreads();
  }
#pragma unroll
  for (int i = 0; i < 2; ++i)
#pragma unroll
    for (int r = 0; r < 4; ++r) {
      int m = m0 + wm + i * 16 + quad * 4 + r;
      if (m < M) {
        int n = wn3 + l15;
        P[(size_t)m * NOUT + n] = acc[i][0][r];
      }
    }
}

// ---------------- MFMA fused edge block: 128-edge tile, 8 waves ----------------
// K=384 in 3 chunks of 128 (c0=h[dst], c1=h[src], c2=rbf_h in-place VALU).
// Full-width single-pass epilogue (redS[128][130] aliased over As|Bs).
// Round-7 form (proven 103.6-105.4us): in-phase c2 VALU gives cross-block phase
// diversity; round-8's prologue hoist (rhpk live across loop) cost 7us.
// launch_bounds note: 2nd arg is waves/SIMD; (512,4) => VGPR cap 128. (512,8)
// capped at 64 and spilled ~700MB/dispatch (round-3 regression).
__global__ __launch_bounds__(512, 4) void k_edge_mfma(
    const ushort* __restrict__ hbf,    // [N][128] bf16
    const ushort* __restrict__ Wlbf,   // [128][384] bf16
    const float* __restrict__ bl,      // [128]
    const float* __restrict__ rbfG,    // [E][6] (sorted)
    const float* __restrict__ Wr,      // [128][6]
    const float* __restrict__ br,      // [128]
    const float* __restrict__ Wrbf,    // [128][6]
    const int* __restrict__ ssrc, const int* __restrict__ sdst,
    float* __restrict__ node,          // [N,128]
    int E, int nb, int perXcd) {
  // As[128 rows][16 units] | Bs[128 rows][16 units] = 32768 ushorts;
  // epilogue alias: redS[128][130] f32 = 33280 ushorts (stride 130 -> 2-way banks)
  __shared__ alignas(16) ushort ABs[33280];
  __shared__ float rbfS[128][6];
  __shared__ int dstS[128];
  __shared__ int srcS[128];

  const int bp = blockIdx.x;
  const int lb = (bp & 7) * perXcd + (bp >> 3);
  if (lb >= nb) return;

  ushort* As = ABs;                 // [128][128] K-major, 16B-unit swizzled (&15)
  ushort* Bs = ABs + 128 * 16 * 8;  // [128 N-rows][128 K]

  const int tid = threadIdx.x;
  const int e0 = lb * 128;

  if (tid < 128) {
    int e = min(e0 + tid, E - 1);
    dstS[tid] = sdst[e];
    srcS[tid] = ssrc[e];
  }
  for (int idx = tid; idx < 128 * NR; idx += 512) {
    int gidx = e0 * NR + idx;
    ((float*)rbfS)[idx] = (gidx < E * NR) ? rbfG[gidx] : 0.f;
  }
  __syncthreads();

  const int w = tid >> 6;           // 8 waves
  const int lane = tid & 63;
  const int l15 = lane & 15, quad = lane >> 4;
  const int wm = (w >> 1) * 32;     // edge strip: 0/32/64/96
  const int wn = (w & 1) * 64;      // col strip: 0 or 64

  floatx4 acc[2][4];
#pragma unroll
  for (int i = 0; i < 2; ++i)
#pragma unroll
    for (int j = 0; j < 4; ++j) acc[i][j] = floatx4{0.f, 0.f, 0.f, 0.f};

  for (int c = 0; c < 3; ++c) {
    // B tile: 128 rows x 128 K = 2048 16B-units, 8 waves x 4 issues
#pragma unroll
    for (int i = 0; i < 4; ++i) {
      int u = w * 256 + i * 64 + lane;
      int nrow = u >> 4, gp = u & 15;
      int g = gp ^ (nrow & 15);
      const ushort* gsrc = Wlbf + (size_t)nrow * 384 + c * 128 + g * 8;
      int lbo = __builtin_amdgcn_readfirstlane(w * 256 + i * 64);
      async_copy16((const void*)gsrc, (void*)(Bs + lbo * 8));
    }
    if (c < 2) {
      // A tile = full h rows gathered via dst (c=0) / src (c=1): 2048 units
      const int* rowS = (c == 0) ? dstS : srcS;
#pragma unroll
      for (int i = 0; i < 4; ++i) {
        int u = w * 256 + i * 64 + lane;
        int nrow = u >> 4;
        int g = (u & 15) ^ (nrow & 15);
        int row = rowS[nrow];
        const ushort* gsrc = hbf + (size_t)row * H + g * 8;
        int lbo = __builtin_amdgcn_readfirstlane(w * 256 + i * 64);
        async_copy16((const void*)gsrc, (void*)(As + lbo * 8));
      }
    } else {
      // A tile = rbf_h = swish(rbf @ Wr^T + br), all 128 cols in one phase.
      // Thread owns col (tid&127), rows (tid>>7)*32..+32. rbfS reads broadcast.
      const int colL = tid & 127;
      float w0 = Wr[colL * NR + 0], w1 = Wr[colL * NR + 1], w2 = Wr[colL * NR + 2];
      float w3 = Wr[colL * NR + 3], w4 = Wr[colL * NR + 4], w5 = Wr[colL * NR + 5];
      float bv = br[colL];
      const int r0 = (tid >> 7) * 32;
#pragma unroll
      for (int r = 0; r < 32; ++r) {
        int m = r0 + r;
        const float2* rp = (const float2*)&rbfS[m][0];
        float2 q0 = rp[0], q1 = rp[1], q2 = rp[2];
        float z = bv + q0.x * w0 + q0.y * w1 + q1.x * w2 + q1.y * w3 + q2.x * w4 + q2.y * w5;
        ushort hv = f2bf_rne(swishf(z));
        As[(m * 16 + ((colL >> 3) ^ (m & 15))) * 8 + (colL & 7)] = hv;
      }
    }
    __syncthreads();
#pragma unroll
    for (int s = 0; s < 4; ++s) {
      const int gg = s * 4 + quad;
      short8 af[2], bfr[4];
#pragma unroll
      for (int i = 0; i < 2; ++i) {
        int m = wm + i * 16 + l15;
        af[i] = *(const short8*)(As + (m * 16 + (gg ^ (m & 15))) * 8);
      }
#pragma unroll
      for (int j = 0; j < 4; ++j) {
        int n = wn + j * 16 + l15;
        bfr[j] = *(const short8*)(Bs + (n * 16 + (gg ^ (n & 15))) * 8);
      }
#pragma unroll
      for (int i = 0; i < 2; ++i)
#pragma unroll
        for (int j = 0; j < 4; ++j)
          acc[i][j] = __builtin_amdgcn_mfma_f32_16x16x32_bf16(af[i], bfr[j], acc[i][j], 0, 0, 0);
    }
    __syncthreads();   // also fences As|Bs reads before redS overwrite (c==2)
  }

  // ---- epilogue: t = swish(z+bl) * (rbf . Wrbf[n]); single full-width pass ----
  float* redS = (float*)ABs;   // [128][130] f32 (stride 130 => 2-way banks)
  float wt[4][NR], blv[4];
#pragma unroll
  for (int j = 0; j < 4; ++j) {
    int n = wn + j * 16 + l15;
    blv[j] = bl[n];
#pragma unroll
    for (int r = 0; r < NR; ++r) wt[j][r] = Wrbf[n * NR + r];
  }

  // all 8 waves write their 32x64 quadrant (rows wm.., cols wn..)
#pragma unroll
  for (int i = 0; i < 2; ++i)
#pragma unroll
    for (int r = 0; r < 4; ++r) {
      int mg = wm + i * 16 + quad * 4 + r;
      float rb[NR];
#pragma unroll
      for (int q = 0; q < NR; ++q) rb[q] = rbfS[mg][q];
#pragma unroll
      for (int j = 0; j < 4; ++j) {
        float z = acc[i][j][r] + blv[j];
        float ev = swishf(z);
        float wv = 0.f;
#pragma unroll
        for (int q = 0; q < NR; ++q) wv += rb[q] * wt[j][q];
        redS[mg * 130 + wn + j * 16 + l15] = ev * wv;  // zero when e>=E (rb==0)
      }
    }
  __syncthreads();

  // reduce: 512 threads, col = tid&127, 4 row-chunks of 32; coalesced atomics
  {
    int cc = tid & 127, chunk = tid >> 7;
    int ml0 = chunk * 32;
    float s = 0.f;
    int prev = dstS[ml0];
#pragma unroll
    for (int ml = ml0; ml < ml0 + 32; ++ml) {
      int d = dstS[ml];
      float v = redS[ml * 130 + cc];
      if (d != prev) {
        atomicAdd(&node[(size_t)prev * H + cc], s);
        s = 0.f;
        prev = d;
      }
      s += v;
    }
    atomicAdd(&node[(size_t)prev * H + cc], s);
  }
}

extern "C" void kernel_launch(void* const* d_in, const int* in_sizes, int n_in,
                              void* d_out, int out_size, void* d_ws, size_t ws_size,
                              hipStream_t stream) {
  const float* x    = (const float*)d_in[0];
  const float* pos  = (const float*)d_in[1];
  const float* freq = (const float*)d_in[2];
  const float* Wx   = (const float*)d_in[3];
  const float* Wr   = (const float*)d_in[4];
  const float* br   = (const float*)d_in[5];
  const float* Wl   = (const float*)d_in[6];
  const float* bl   = (const float*)d_in[7];
  const float* Wrbf = (const float*)d_in[8];
  const float* Wls  = (const float*)d_in[9];
  const float* bls  = (const float*)d_in[10];
  const float* Wout = (const float*)d_in[11];
  const int* esrc = (const int*)d_in[12];
  const int* edst = (const int*)d_in[13];
  const int* ii   = (const int*)d_in[14];
  const int* jjv  = (const int*)d_in[15];
  const int* kkv  = (const int*)d_in[16];

  const int N = in_sizes[0] / H;
  const int E = in_sizes[12];
  const int T = in_sizes[14];

  float* out   = (float*)d_out;
  float* P     = out;                       // [N,64]
  float* angle = out + (size_t)N * NOUT;    // [T]

  float* ws = (float*)d_ws;
  float* rbfG  = ws; ws += (size_t)E * NR;
  float* nodeA = ws; ws += (size_t)N * H;
  ushort* u = (ushort*)ws;
  ushort* hbf    = u; u += (size_t)N * H;
  ushort* Wlbf   = u; u += 3 * H * H;
  ushort* Wxhi   = u; u += H * H;
  ushort* Wxlo   = u; u += H * H;
  ushort* Wlshi  = u; u += 3 * H * H;
  ushort* Wlslo  = u; u += 3 * H * H;
  ushort* Wouthi = u; u += NOUT * H;
  ushort* Woutlo = u; u += NOUT * H;
  int* ip = (int*)u;
  int* cnt   = ip; ip += N;
  int* cur   = ip; ip += N;
  int* ssrcA = ip; ip += E;
  int* sdstA = ip; ip += E;

  // fused zeros + weight prep
  {
    int n4 = N * H / 4;
    k_init<<<(n4 + 255) / 256, 256, 0, stream>>>((float4*)nodeA, n4, cnt, N,
                                                 Wl, Wx, Wls, Wout, Wlbf,
                                                 Wxhi, Wxlo, Wlshi, Wlslo, Wouthi, Woutlo);
  }

  // counting sort of edges by dst
  k_hist<<<(E + 255) / 256, 256, 0, stream>>>(edst, cnt, E);
  k_scan<<<1, 1024, 0, stream>>>(cnt, cur, N);

  // fused scatter + per-edge rbf (written directly at sorted slot) + angles
  {
    int EB = (E + 255) / 256;
    int TB = (T + 255) / 256;
    k_scatter_feat_ang<<<EB + TB, 256, 0, stream>>>(pos, esrc, edst, freq, cur,
                                                    rbfG, ssrcA, sdstA, E, EB,
                                                    ii, jjv, kkv, angle, T);
  }

  // h = x @ Wx^T -> bf16 (128-row tiles, 512 threads)
  k_x_gemm<<<(N + 127) / 128, 512, 0, stream>>>(x, Wxhi, Wxlo, hbf, N);

  // fused MFMA edge block (128-edge tiles, XCD swizzle) -> segmented sum into nodeA
  {
    int nb = (E + 127) / 128;
    int perXcd = (nb + 7) / 8;
    int grid = perXcd * 8;
    k_edge_mfma<<<grid, 512, 0, stream>>>(hbf, Wlbf, bl, rbfG, Wr, br, Wrbf,
                                          ssrcA, sdstA, nodeA, E, nb, perXcd);
  }

  // fused node MLP (512 threads, 2x4 wave quadrants)
  k_node_mlp<<<(N + 63) / 64, 512, 0, stream>>>(nodeA, Wlshi, Wlslo, Wouthi, Woutlo,
                                                bls, P, N);
}

// Round 13
// 347.385 us; speedup vs baseline: 1.1381x; 1.1381x over previous
//
#include <hip/hip_runtime.h>
#include <hip/hip_bf16.h>
#include <math.h>

#define H   128
#define NR  6
#define NOUT 64

typedef __attribute__((ext_vector_type(8))) short short8;
typedef __attribute__((ext_vector_type(4))) float floatx4;

// swish with fast rcp: outputs feed bf16 (4e-3) or bf16-split (1.5e-5) paths;
// v_rcp_f32 (~1e-7 rel err) replaces the ~10-inst IEEE div sequence.
__device__ __forceinline__ float swishf(float z) {
  float t = __expf(-z);
  return z * __builtin_amdgcn_rcpf(1.0f + t);
}

__device__ __forceinline__ ushort f2bf(float x) {
  __hip_bfloat16 b = __float2bfloat16(x);
  return *reinterpret_cast<ushort*>(&b);
}

// fast RNE float->bf16 (no NaN handling; inputs are finite here)
__device__ __forceinline__ ushort f2bf_rne(float x) {
  unsigned int u = __float_as_uint(x);
  u += 0x7FFFu + ((u >> 16) & 1u);
  return (ushort)(u >> 16);
}

__device__ __forceinline__ float bf2f(ushort u) {
  unsigned int v = ((unsigned int)u) << 16;
  return __uint_as_float(v);
}

// async 16B global->LDS (wave-uniform LDS base + lane*16)
__device__ __forceinline__ void async_copy16(const void* g, void* l) {
  __builtin_amdgcn_global_load_lds(
      (const __attribute__((address_space(1))) unsigned int*)g,
      (__attribute__((address_space(3))) unsigned int*)l, 16, 0, 0);
}

// ---------------- fused init: zero nodeA + cnt, weight conversions ----------------
__global__ void k_init(float4* __restrict__ nodeA, int n4, int* __restrict__ cnt, int n,
                       const float* __restrict__ Wl, const float* __restrict__ Wx,
                       const float* __restrict__ Wls, const float* __restrict__ Wout,
                       ushort* __restrict__ Wlbf,
                       ushort* __restrict__ Wxhi, ushort* __restrict__ Wxlo,
                       ushort* __restrict__ Wlshi, ushort* __restrict__ Wlslo,
                       ushort* __restrict__ Wouthi, ushort* __restrict__ Woutlo) {
  int i = blockIdx.x * blockDim.x + threadIdx.x;
  if (i < n4) nodeA[i] = make_float4(0.f, 0.f, 0.f, 0.f);
  if (i < n) cnt[i] = 0;
  int idx = i;
  if (idx < 49152) {
    Wlbf[idx] = f2bf(Wl[idx]);
    return;
  }
  idx -= 49152;
  if (idx < 16384) {
    float x = Wx[idx];
    ushort h = f2bf(x);
    Wxhi[idx] = h; Wxlo[idx] = f2bf(x - bf2f(h));
    return;
  }
  idx -= 16384;
  if (idx < 49152) {
    float x = Wls[idx];
    ushort h = f2bf(x);
    Wlshi[idx] = h; Wlslo[idx] = f2bf(x - bf2f(h));
    return;
  }
  idx -= 49152;
  if (idx < 8192) {
    float x = Wout[idx];
    ushort h = f2bf(x);
    Wouthi[idx] = h; Woutlo[idx] = f2bf(x - bf2f(h));
  }
}

// ---------------- counting sort by dst: hist / 2-level parallel scan ----------------
__global__ void k_hist(const int* __restrict__ dst, int* __restrict__ cnt, int E) {
  int i = blockIdx.x * blockDim.x + threadIdx.x;
  if (i < E) atomicAdd(&cnt[dst[i]], 1);
}

// Level A: per-block (1024 elems) local exclusive scan + block total.
// Replaces the 1-block 49-serial-tile scan (~18us of whole-GPU serialization,
// one CU working, HBM latency per tile) with one parallel pass (~3us).
__global__ __launch_bounds__(1024) void k_scanA(const int* __restrict__ cnt,
                                                int* __restrict__ cur,
                                                int* __restrict__ bsum, int N) {
  __shared__ int wsum[16];
  const int tid = threadIdx.x;
  const int gid = blockIdx.x * 1024 + tid;
  const int lane = tid & 63, wv = tid >> 6;
  int v0 = (gid < N) ? cnt[gid] : 0;
  int v = v0;
#pragma unroll
  for (int off = 1; off < 64; off <<= 1) {
    int t = __shfl_up(v, off, 64);
    if (lane >= off) v += t;
  }
  if (lane == 63) wsum[wv] = v;
  __syncthreads();
  if (wv == 0 && lane < 16) {
    int t = wsum[lane];
#pragma unroll
    for (int off = 1; off < 16; off <<= 1) {
      int u2 = __shfl_up(t, off, 64);
      if (lane >= off) t += u2;
    }
    wsum[lane] = t;  // inclusive wave sums
  }
  __syncthreads();
  int excl = (wv > 0 ? wsum[wv - 1] : 0) + (v - v0);  // block-local exclusive
  if (gid < N) cur[gid] = excl;
  if (tid == 0) bsum[blockIdx.x] = wsum[15];           // block total
}

// Level B: 1 wave scans the block totals -> exclusive block offsets.
// The offset-apply is folded into k_scatter_feat_ang (boff[d>>10] add, L1-hot).
__global__ void k_scanB(const int* __restrict__ bsum, int* __restrict__ boff, int nb) {
  const int lane = threadIdx.x & 63;
  int base = 0;
  for (int t0 = 0; t0 < nb; t0 += 64) {
    int v = (t0 + lane < nb) ? bsum[t0 + lane] : 0;
    int v0 = v;
#pragma unroll
    for (int off = 1; off < 64; off <<= 1) {
      int t = __shfl_up(v, off, 64);
      if (lane >= off) v += t;
    }
    if (t0 + lane < nb) boff[t0 + lane] = base + v - v0;
    base += __shfl(v, 63, 64);
  }
}

// ---------------- fused scatter + per-edge rbf + triplet angles ----------------
// For edge i: p = boff[d>>10] + atomicAdd(cur[d]) gives its sorted slot; write
// rbf/ssrc/sdst directly at p (no perm array, no extra E-pass).
__global__ __launch_bounds__(256) void k_scatter_feat_ang(
    const float* __restrict__ pos, const int* __restrict__ esrc,
    const int* __restrict__ edst, const float* __restrict__ freq,
    int* __restrict__ cur, const int* __restrict__ boff,
    float* __restrict__ rbfG,       // [E][6] sorted
    int* __restrict__ ssrc, int* __restrict__ sdst, int E, int EB,
    const int* __restrict__ ii, const int* __restrict__ jj, const int* __restrict__ kk,
    float* __restrict__ ang, int T) {
  if (blockIdx.x < (unsigned)EB) {
    int i = blockIdx.x * 256 + threadIdx.x;
    if (i >= E) return;
    const int s = esrc[i], d = edst[i];
    const int p = atomicAdd(&cur[d], 1) + boff[d >> 10];
    float dx = pos[d * 3 + 0] - pos[s * 3 + 0];
    float dy = pos[d * 3 + 1] - pos[s * 3 + 1];
    float dz = pos[d * 3 + 2] - pos[s * 3 + 2];
    float dist = sqrtf(dx * dx + dy * dy + dz * dz);
    float dn = dist * 0.2f;
    float inv = __builtin_amdgcn_rcpf(dn);   // feeds bf16-precision path; rcp ok
    float dn2 = dn * dn;
    float dp = dn2 * dn2 * dn;  // dn^5
    float env = inv - 21.0f * dp + 35.0f * dp * dn - 15.0f * dp * dn2;
#pragma unroll
    for (int r = 0; r < NR; ++r)
      rbfG[(size_t)p * NR + r] = env * __sinf(freq[r] * dn);  // fast sin: arg < 19 rad
    ssrc[p] = s;
    sdst[p] = d;
  } else {
    int t = (blockIdx.x - EB) * 256 + threadIdx.x;
    if (t >= T) return;
    int i = ii[t], j = jj[t], k = kk[t];
    float pix = pos[i * 3], piy = pos[i * 3 + 1], piz = pos[i * 3 + 2];
    float vjx = pos[j * 3] - pix, vjy = pos[j * 3 + 1] - piy, vjz = pos[j * 3 + 2] - piz;
    float vkx = pos[k * 3] - pix, vky = pos[k * 3 + 1] - piy, vkz = pos[k * 3 + 2] - piz;
    float a = vjx * vkx + vjy * vky + vjz * vkz;
    float cx = vjy * vkz - vjz * vky;
    float cy = vjz * vkx - vjx * vkz;
    float cz = vjx * vky - vjy * vkx;
    float b = sqrtf(cx * cx + cy * cy + cz * cz);
    ang[t] = atan2f(b, a);   // direct output: keep libm accuracy
  }
}

// ---------------- x @ Wx^T -> bf16, 128-row tiles, 512 threads ----------------
__global__ __launch_bounds__(512, 4) void k_x_gemm(
    const float* __restrict__ A,      // [M][128] fp32
    const ushort* __restrict__ Bhi,   // [128][128]
    const ushort* __restrict__ Blo,
    ushort* __restrict__ C,           // [M][128] bf16
    int M) {
  __shared__ alignas(16) ushort Ah[128 * 32];
  __shared__ alignas(16) ushort Al[128 * 32];
  __shared__ alignas(16) ushort Bh[128 * 32];
  __shared__ alignas(16) ushort Bl[128 * 32];

  const int tid = threadIdx.x;
  const int m0 = blockIdx.x * 128;
  const int w = tid >> 6, lane = tid & 63;
  const int l15 = lane & 15, quad = lane >> 4;
  const int wm = (w >> 1) * 32;   // 4 row strips over 128
  const int wn = (w & 1) * 64;    // 2 col halves

  floatx4 acc[2][4];
#pragma unroll
  for (int i = 0; i < 2; ++i)
#pragma unroll
    for (int j = 0; j < 4; ++j) acc[i][j] = floatx4{0.f, 0.f, 0.f, 0.f};

  for (int c = 0; c < 4; ++c) {
    const int kb = c * 32;
    {
      int row = tid >> 2, g = tid & 3;   // 128 rows x 4 K-groups
      int m = m0 + row;
      float4 v0 = make_float4(0.f, 0.f, 0.f, 0.f), v1 = v0;
      if (m < M) {
        v0 = *(const float4*)&A[(size_t)m * 128 + kb + g * 8];
        v1 = *(const float4*)&A[(size_t)m * 128 + kb + g * 8 + 4];
      }
      float xs[8] = {v0.x, v0.y, v0.z, v0.w, v1.x, v1.y, v1.z, v1.w};
      short8 hi, lo;
#pragma unroll
      for (int j = 0; j < 8; ++j) {
        ushort h = f2bf_rne(xs[j]);
        hi[j] = (short)h;
        lo[j] = (short)f2bf_rne(xs[j] - bf2f(h));
      }
      int slot = row * 4 + (g ^ ((row >> 1) & 3));
      *(short8*)(Ah + slot * 8) = hi;
      *(short8*)(Al + slot * 8) = lo;
    }
    {
      // B: 128 rows x 32 K = 512 16B-units, 8 waves x 1 issue
      int s = w * 64 + lane;
      int brow = s >> 2, gp = s & 3;
      int gg = gp ^ ((brow >> 1) & 3);
      int lb = __builtin_amdgcn_readfirstlane(w * 64);
      async_copy16((const void*)(Bhi + (size_t)brow * 128 + kb + gg * 8), (void*)(Bh + lb * 8));
      async_copy16((const void*)(Blo + (size_t)brow * 128 + kb + gg * 8), (void*)(Bl + lb * 8));
    }
    __syncthreads();
    short8 ah[2], al[2], bh[4], blv[4];
#pragma unroll
    for (int i = 0; i < 2; ++i) {
      int m = wm + i * 16 + l15;
      int slot = m * 4 + (quad ^ ((m >> 1) & 3));
      ah[i] = *(const short8*)(Ah + slot * 8);
      al[i] = *(const short8*)(Al + slot * 8);
    }
#pragma unroll
    for (int j = 0; j < 4; ++j) {
      int n = wn + j * 16 + l15;
      int slot = n * 4 + (quad ^ ((n >> 1) & 3));
      bh[j] = *(const short8*)(Bh + slot * 8);
      blv[j] = *(const short8*)(Bl + slot * 8);
    }
#pragma unroll
    for (int i = 0; i < 2; ++i)
#pragma unroll
      for (int j = 0; j < 4; ++j) {
        acc[i][j] = __builtin_amdgcn_mfma_f32_16x16x32_bf16(ah[i], bh[j], acc[i][j], 0, 0, 0);
        acc[i][j] = __builtin_amdgcn_mfma_f32_16x16x32_bf16(ah[i], blv[j], acc[i][j], 0, 0, 0);
        acc[i][j] = __builtin_amdgcn_mfma_f32_16x16x32_bf16(al[i], bh[j], acc[i][j], 0, 0, 0);
      }
    __syncthreads();
  }

#pragma unroll
  for (int i = 0; i < 2; ++i)
#pragma unroll
    for (int r = 0; r < 4; ++r) {
      int m = m0 + wm + i * 16 + quad * 4 + r;
      if (m < M) {
#pragma unroll
        for (int j = 0; j < 4; ++j) {
          int n = wn + j * 16 + l15;
          C[(size_t)m * 128 + n] = f2bf_rne(acc[i][j][r]);
        }
      }
    }
}

// ---------------- fused node MLP: 3x (swish o Wls) + Wout, 512 threads ----------
__global__ __launch_bounds__(512, 4) void k_node_mlp(
    const float* __restrict__ nodeA,   // [M][128]
    const ushort* __restrict__ Wlshi,  // [3][128][128]
    const ushort* __restrict__ Wlslo,
    const ushort* __restrict__ Wouthi, // [64][128]
    const ushort* __restrict__ Woutlo,
    const float* __restrict__ bls,     // [3][128]
    float* __restrict__ P,             // [M][64]
    int M) {
  __shared__ alignas(16) ushort AactH[64 * 16 * 8];
  __shared__ alignas(16) ushort AactL[64 * 16 * 8];
  __shared__ alignas(16) ushort Bh[128 * 4 * 8];
  __shared__ alignas(16) ushort Bl[128 * 4 * 8];
  __shared__ float blsS[3 * 128];

  const int tid = threadIdx.x;
  const int m0 = blockIdx.x * 64;
  const int w = tid >> 6, lane = tid & 63;
  const int l15 = lane & 15, quad = lane >> 4;
  const int wm = (w >> 2) * 32;   // 2 row strips over 64
  const int wn = (w & 3) * 32;    // 4 col strips over 128

  for (int i = tid; i < 3 * 128; i += 512) blsS[i] = bls[i];

  floatx4 acc[2][2];

  for (int p = 0; p < 3; ++p) {
    const ushort* Bhg = Wlshi + p * 128 * 128;
    const ushort* Blg = Wlslo + p * 128 * 128;
#pragma unroll
    for (int i = 0; i < 2; ++i)
#pragma unroll
      for (int j = 0; j < 2; ++j) acc[i][j] = floatx4{0.f, 0.f, 0.f, 0.f};

    for (int c = 0; c < 4; ++c) {
      const int kb = c * 32;
      {
        // B: 128 rows x 32 K = 512 units, 8 waves x 1 issue
        int s = w * 64 + lane;
        int brow = s >> 2, gp = s & 3;
        int gg = gp ^ ((brow >> 1) & 3);
        int lb = __builtin_amdgcn_readfirstlane(w * 64);
        async_copy16((const void*)(Bhg + (size_t)brow * 128 + kb + gg * 8), (void*)(Bh + lb * 8));
        async_copy16((const void*)(Blg + (size_t)brow * 128 + kb + gg * 8), (void*)(Bl + lb * 8));
      }
      __syncthreads();
      short8 ah[2], al[2];
      if (p == 0) {
#pragma unroll
        for (int i = 0; i < 2; ++i) {
          int m = m0 + wm + i * 16 + l15;
          float4 v0 = make_float4(0.f, 0.f, 0.f, 0.f), v1 = v0;
          if (m < M) {
            v0 = *(const float4*)&nodeA[(size_t)m * 128 + kb + quad * 8];
            v1 = *(const float4*)&nodeA[(size_t)m * 128 + kb + quad * 8 + 4];
          }
          float xs[8] = {v0.x, v0.y, v0.z, v0.w, v1.x, v1.y, v1.z, v1.w};
#pragma unroll
          for (int j = 0; j < 8; ++j) {
            ushort hh = f2bf_rne(xs[j]);
            ah[i][j] = (short)hh;
            al[i][j] = (short)f2bf_rne(xs[j] - bf2f(hh));
          }
        }
      } else {
#pragma unroll
        for (int i = 0; i < 2; ++i) {
          int arow = wm + i * 16 + l15;
          int g16 = c * 4 + quad;
          int slot = arow * 16 + (g16 ^ (arow & 15));
          ah[i] = *(const short8*)(AactH + slot * 8);
          al[i] = *(const short8*)(AactL + slot * 8);
        }
      }
      short8 bh[2], blv[2];
#pragma unroll
      for (int j = 0; j < 2; ++j) {
        int n = wn + j * 16 + l15;
        int slot = n * 4 + (quad ^ ((n >> 1) & 3));
        bh[j] = *(const short8*)(Bh + slot * 8);
        blv[j] = *(const short8*)(Bl + slot * 8);
      }
#pragma unroll
      for (int i = 0; i < 2; ++i)
#pragma unroll
        for (int j = 0; j < 2; ++j) {
          acc[i][j] = __builtin_amdgcn_mfma_f32_16x16x32_bf16(ah[i], bh[j], acc[i][j], 0, 0, 0);
          acc[i][j] = __builtin_amdgcn_mfma_f32_16x16x32_bf16(ah[i], blv[j], acc[i][j], 0, 0, 0);
          acc[i][j] = __builtin_amdgcn_mfma_f32_16x16x32_bf16(al[i], bh[j], acc[i][j], 0, 0, 0);
        }
      __syncthreads();
    }
#pragma unroll
    for (int i = 0; i < 2; ++i)
#pragma unroll
      for (int r = 0; r < 4; ++r) {
        int row = wm + i * 16 + quad * 4 + r;
#pragma unroll
        for (int j = 0; j < 2; ++j) {
          int col = wn + j * 16 + l15;
          float z = acc[i][j][r] + blsS[p * 128 + col];
          z = swishf(z);
          ushort hh = f2bf_rne(z);
          int slot = row * 16 + ((col >> 3) ^ (row & 15));
          AactH[slot * 8 + (col & 7)] = hh;
          AactL[slot * 8 + (col & 7)] = f2bf_rne(z - bf2f(hh));
        }
      }
    __syncthreads();
  }

  const int wn3 = (w & 3) * 16;   // 4 col strips of 16 over 64
#pragma unroll
  for (int i = 0; i < 2; ++i) acc[i][0] = floatx4{0.f, 0.f, 0.f, 0.f};

  for (int c = 0; c < 4; ++c) {
    const int kb = c * 32;
    if (w < 4) {
      // Wout: 64 rows x 32 K = 256 units, waves 0-3 x 1 issue
      int s = w * 64 + lane;
      int brow = s >> 2, gp = s & 3;
      int gg = gp ^ ((brow >> 1) & 3);
      int lb = __builtin_amdgcn_readfirstlane(w * 64);
      async_copy16((const void*)(Wouthi + (size_t)brow * 128 + kb + gg * 8), (void*)(Bh + lb * 8));
      async_copy16((const void*)(Woutlo + (size_t)brow * 128 + kb + gg * 8), (void*)(Bl + lb * 8));
    }
    __syncthreads();
    short8 ah[2], al[2], bh, blv;
#pragma unroll
    for (int i = 0; i < 2; ++i) {
      int arow = wm + i * 16 + l15;
      int g16 = c * 4 + quad;
      int slot = arow * 16 + (g16 ^ (arow & 15));
      ah[i] = *(const short8*)(AactH + slot * 8);
      al[i] = *(const short8*)(AactL + slot * 8);
    }
    {
      int n = wn3 + l15;
      int slot = n * 4 + (quad ^ ((n >> 1) & 3));
      bh = *(const short8*)(Bh + slot * 8);
      blv = *(const short8*)(Bl + slot * 8);
    }
#pragma unroll
    for (int i = 0; i < 2; ++i) {
      acc[i][0] = __builtin_amdgcn_mfma_f32_16x16x32_bf16(ah[i], bh, acc[i][0], 0, 0, 0);
      acc[i][0] = __builtin_amdgcn_mfma_f32_16x16x32_bf16(ah[i], blv, acc[i][0], 0, 0, 0);
      acc[i][0] = __builtin_amdgcn_mfma_f32_16x16x32_bf16(al[i], bh, acc[i][0], 0, 0, 0);
    }
    __syncthreads();
  }
#pragma unroll
  for (int i = 0; i < 2; ++i)
#pragma unroll
    for (int r = 0; r < 4; ++r) {
      int m = m0 + wm + i * 16 + quad * 4 + r;
      if (m < M) {
        int n = wn3 + l15;
        P[(size_t)m * NOUT + n] = acc[i][0][r];
      }
    }
}

// ---------------- MFMA fused edge block: 128-edge tile, 8 waves ----------------
// K=384 in 3 chunks of 128 (c0=h[dst], c1=h[src], c2=rbf_h in-place VALU).
// Full-width single-pass epilogue (redS[128][130] aliased over As|Bs).
// Round-7 form (proven 103.6-105.7us): in-phase c2 VALU gives cross-block phase
// diversity; round-8's prologue hoist (rhpk live across loop) cost 7us.
// launch_bounds note: 2nd arg is waves/SIMD; (512,4) => VGPR cap 128. (512,8)
// capped at 64 and spilled ~700MB/dispatch (round-3 regression).
__global__ __launch_bounds__(512, 4) void k_edge_mfma(
    const ushort* __restrict__ hbf,    // [N][128] bf16
    const ushort* __restrict__ Wlbf,   // [128][384] bf16
    const float* __restrict__ bl,      // [128]
    const float* __restrict__ rbfG,    // [E][6] (sorted)
    const float* __restrict__ Wr,      // [128][6]
    const float* __restrict__ br,      // [128]
    const float* __restrict__ Wrbf,    // [128][6]
    const int* __restrict__ ssrc, const int* __restrict__ sdst,
    float* __restrict__ node,          // [N,128]
    int E, int nb, int perXcd) {
  // As[128 rows][16 units] | Bs[128 rows][16 units] = 32768 ushorts;
  // epilogue alias: redS[128][130] f32 = 33280 ushorts (stride 130 -> 2-way banks)
  __shared__ alignas(16) ushort ABs[33280];
  __shared__ float rbfS[128][6];
  __shared__ int dstS[128];
  __shared__ int srcS[128];

  const int bp = blockIdx.x;
  const int lb = (bp & 7) * perXcd + (bp >> 3);
  if (lb >= nb) return;

  ushort* As = ABs;                 // [128][128] K-major, 16B-unit swizzled (&15)
  ushort* Bs = ABs + 128 * 16 * 8;  // [128 N-rows][128 K]

  const int tid = threadIdx.x;
  const int e0 = lb * 128;

  if (tid < 128) {
    int e = min(e0 + tid, E - 1);
    dstS[tid] = sdst[e];
    srcS[tid] = ssrc[e];
  }
  for (int idx = tid; idx < 128 * NR; idx += 512) {
    int gidx = e0 * NR + idx;
    ((float*)rbfS)[idx] = (gidx < E * NR) ? rbfG[gidx] : 0.f;
  }
  __syncthreads();

  const int w = tid >> 6;           // 8 waves
  const int lane = tid & 63;
  const int l15 = lane & 15, quad = lane >> 4;
  const int wm = (w >> 1) * 32;     // edge strip: 0/32/64/96
  const int wn = (w & 1) * 64;      // col strip: 0 or 64

  floatx4 acc[2][4];
#pragma unroll
  for (int i = 0; i < 2; ++i)
#pragma unroll
    for (int j = 0; j < 4; ++j) acc[i][j] = floatx4{0.f, 0.f, 0.f, 0.f};

  for (int c = 0; c < 3; ++c) {
    // B tile: 128 rows x 128 K = 2048 16B-units, 8 waves x 4 issues
#pragma unroll
    for (int i = 0; i < 4; ++i) {
      int u = w * 256 + i * 64 + lane;
      int nrow = u >> 4, gp = u & 15;
      int g = gp ^ (nrow & 15);
      const ushort* gsrc = Wlbf + (size_t)nrow * 384 + c * 128 + g * 8;
      int lbo = __builtin_amdgcn_readfirstlane(w * 256 + i * 64);
      async_copy16((const void*)gsrc, (void*)(Bs + lbo * 8));
    }
    if (c < 2) {
      // A tile = full h rows gathered via dst (c=0) / src (c=1): 2048 units
      const int* rowS = (c == 0) ? dstS : srcS;
#pragma unroll
      for (int i = 0; i < 4; ++i) {
        int u = w * 256 + i * 64 + lane;
        int nrow = u >> 4;
        int g = (u & 15) ^ (nrow & 15);
        int row = rowS[nrow];
        const ushort* gsrc = hbf + (size_t)row * H + g * 8;
        int lbo = __builtin_amdgcn_readfirstlane(w * 256 + i * 64);
        async_copy16((const void*)gsrc, (void*)(As + lbo * 8));
      }
    } else {
      // A tile = rbf_h = swish(rbf @ Wr^T + br), all 128 cols in one phase.
      // Thread owns col (tid&127), rows (tid>>7)*32..+32. rbfS reads broadcast.
      const int colL = tid & 127;
      float w0 = Wr[colL * NR + 0], w1 = Wr[colL * NR + 1], w2 = Wr[colL * NR + 2];
      float w3 = Wr[colL * NR + 3], w4 = Wr[colL * NR + 4], w5 = Wr[colL * NR + 5];
      float bv = br[colL];
      const int r0 = (tid >> 7) * 32;
#pragma unroll
      for (int r = 0; r < 32; ++r) {
        int m = r0 + r;
        const float2* rp = (const float2*)&rbfS[m][0];
        float2 q0 = rp[0], q1 = rp[1], q2 = rp[2];
        float z = bv + q0.x * w0 + q0.y * w1 + q1.x * w2 + q1.y * w3 + q2.x * w4 + q2.y * w5;
        ushort hv = f2bf_rne(swishf(z));
        As[(m * 16 + ((colL >> 3) ^ (m & 15))) * 8 + (colL & 7)] = hv;
      }
    }
    __syncthreads();
#pragma unroll
    for (int s = 0; s < 4; ++s) {
      const int gg = s * 4 + quad;
      short8 af[2], bfr[4];
#pragma unroll
      for (int i = 0; i < 2; ++i) {
        int m = wm + i * 16 + l15;
        af[i] = *(const short8*)(As + (m * 16 + (gg ^ (m & 15))) * 8);
      }
#pragma unroll
      for (int j = 0; j < 4; ++j) {
        int n = wn + j * 16 + l15;
        bfr[j] = *(const short8*)(Bs + (n * 16 + (gg ^ (n & 15))) * 8);
      }
#pragma unroll
      for (int i = 0; i < 2; ++i)
#pragma unroll
        for (int j = 0; j < 4; ++j)
          acc[i][j] = __builtin_amdgcn_mfma_f32_16x16x32_bf16(af[i], bfr[j], acc[i][j], 0, 0, 0);
    }
    __syncthreads();   // also fences As|Bs reads before redS overwrite (c==2)
  }

  // ---- epilogue: t = swish(z+bl) * (rbf . Wrbf[n]); single full-width pass ----
  float* redS = (float*)ABs;   // [128][130] f32 (stride 130 => 2-way banks)
  float wt[4][NR], blv[4];
#pragma unroll
  for (int j = 0; j < 4; ++j) {
    int n = wn + j * 16 + l15;
    blv[j] = bl[n];
#pragma unroll
    for (int r = 0; r < NR; ++r) wt[j][r] = Wrbf[n * NR + r];
  }

  // all 8 waves write their 32x64 quadrant (rows wm.., cols wn..)
#pragma unroll
  for (int i = 0; i < 2; ++i)
#pragma unroll
    for (int r = 0; r < 4; ++r) {
      int mg = wm + i * 16 + quad * 4 + r;
      float rb[NR];
#pragma unroll
      for (int q = 0; q < NR; ++q) rb[q] = rbfS[mg][q];
#pragma unroll
      for (int j = 0; j < 4; ++j) {
        float z = acc[i][j][r] + blv[j];
        float ev = swishf(z);
        float wv = 0.f;
#pragma unroll
        for (int q = 0; q < NR; ++q) wv += rb[q] * wt[j][q];
        redS[mg * 130 + wn + j * 16 + l15] = ev * wv;  // zero when e>=E (rb==0)
      }
    }
  __syncthreads();

  // reduce: 512 threads, col = tid&127, 4 row-chunks of 32; coalesced atomics
  {
    int cc = tid & 127, chunk = tid >> 7;
    int ml0 = chunk * 32;
    float s = 0.f;
    int prev = dstS[ml0];
#pragma unroll
    for (int ml = ml0; ml < ml0 + 32; ++ml) {
      int d = dstS[ml];
      float v = redS[ml * 130 + cc];
      if (d != prev) {
        atomicAdd(&node[(size_t)prev * H + cc], s);
        s = 0.f;
        prev = d;
      }
      s += v;
    }
    atomicAdd(&node[(size_t)prev * H + cc], s);
  }
}

extern "C" void kernel_launch(void* const* d_in, const int* in_sizes, int n_in,
                              void* d_out, int out_size, void* d_ws, size_t ws_size,
                              hipStream_t stream) {
  const float* x    = (const float*)d_in[0];
  const float* pos  = (const float*)d_in[1];
  const float* freq = (const float*)d_in[2];
  const float* Wx   = (const float*)d_in[3];
  const float* Wr   = (const float*)d_in[4];
  const float* br   = (const float*)d_in[5];
  const float* Wl   = (const float*)d_in[6];
  const float* bl   = (const float*)d_in[7];
  const float* Wrbf = (const float*)d_in[8];
  const float* Wls  = (const float*)d_in[9];
  const float* bls  = (const float*)d_in[10];
  const float* Wout = (const float*)d_in[11];
  const int* esrc = (const int*)d_in[12];
  const int* edst = (const int*)d_in[13];
  const int* ii   = (const int*)d_in[14];
  const int* jjv  = (const int*)d_in[15];
  const int* kkv  = (const int*)d_in[16];

  const int N = in_sizes[0] / H;
  const int E = in_sizes[12];
  const int T = in_sizes[14];

  float* out   = (float*)d_out;
  float* P     = out;                       // [N,64]
  float* angle = out + (size_t)N * NOUT;    // [T]

  float* ws = (float*)d_ws;
  float* rbfG  = ws; ws += (size_t)E * NR;
  float* nodeA = ws; ws += (size_t)N * H;
  ushort* u = (ushort*)ws;
  ushort* hbf    = u; u += (size_t)N * H;
  ushort* Wlbf   = u; u += 3 * H * H;
  ushort* Wxhi   = u; u += H * H;
  ushort* Wxlo   = u; u += H * H;
  ushort* Wlshi  = u; u += 3 * H * H;
  ushort* Wlslo  = u; u += 3 * H * H;
  ushort* Wouthi = u; u += NOUT * H;
  ushort* Woutlo = u; u += NOUT * H;
  int* ip = (int*)u;
  int* cnt   = ip; ip += N;
  int* cur   = ip; ip += N;
  int* bsum  = ip; ip += 256;
  int* boff  = ip; ip += 256;
  int* ssrcA = ip; ip += E;
  int* sdstA = ip; ip += E;

  // fused zeros + weight prep
  {
    int n4 = N * H / 4;
    k_init<<<(n4 + 255) / 256, 256, 0, stream>>>((float4*)nodeA, n4, cnt, N,
                                                 Wl, Wx, Wls, Wout, Wlbf,
                                                 Wxhi, Wxlo, Wlshi, Wlslo, Wouthi, Woutlo);
  }

  // counting sort of edges by dst: hist + 2-level parallel scan
  const int nscan = (N + 1023) / 1024;
  k_hist<<<(E + 255) / 256, 256, 0, stream>>>(edst, cnt, E);
  k_scanA<<<nscan, 1024, 0, stream>>>(cnt, cur, bsum, N);
  k_scanB<<<1, 64, 0, stream>>>(bsum, boff, nscan);

  // fused scatter + per-edge rbf (written directly at sorted slot) + angles
  {
    int EB = (E + 255) / 256;
    int TB = (T + 255) / 256;
    k_scatter_feat_ang<<<EB + TB, 256, 0, stream>>>(pos, esrc, edst, freq, cur, boff,
                                                    rbfG, ssrcA, sdstA, E, EB,
                                                    ii, jjv, kkv, angle, T);
  }

  // h = x @ Wx^T -> bf16 (128-row tiles, 512 threads)
  k_x_gemm<<<(N + 127) / 128, 512, 0, stream>>>(x, Wxhi, Wxlo, hbf, N);

  // fused MFMA edge block (128-edge tiles, XCD swizzle) -> segmented sum into nodeA
  {
    int nb = (E + 127) / 128;
    int perXcd = (nb + 7) / 8;
    int grid = perXcd * 8;
    k_edge_mfma<<<grid, 512, 0, stream>>>(hbf, Wlbf, bl, rbfG, Wr, br, Wrbf,
                                          ssrcA, sdstA, nodeA, E, nb, perXcd);
  }

  // fused node MLP (512 threads, 2x4 wave quadrants)
  k_node_mlp<<<(N + 63) / 64, 512, 0, stream>>>(nodeA, Wlshi, Wlslo, Wouthi, Woutlo,
                                                bls, P, N);
}

// Round 14
// 341.374 us; speedup vs baseline: 1.1581x; 1.0176x over previous
//
#include <hip/hip_runtime.h>
#include <hip/hip_bf16.h>
#include <math.h>

#define H   128
#define NR  6
#define NOUT 64

typedef __attribute__((ext_vector_type(8))) short short8;
typedef __attribute__((ext_vector_type(4))) float floatx4;

// swish with fast rcp: outputs feed bf16 (4e-3) or bf16-split (1.5e-5) paths;
// v_rcp_f32 (~1e-7 rel err) replaces the ~10-inst IEEE div sequence.
__device__ __forceinline__ float swishf(float z) {
  float t = __expf(-z);
  return z * __builtin_amdgcn_rcpf(1.0f + t);
}

__device__ __forceinline__ ushort f2bf(float x) {
  __hip_bfloat16 b = __float2bfloat16(x);
  return *reinterpret_cast<ushort*>(&b);
}

// fast RNE float->bf16 (no NaN handling; inputs are finite here)
__device__ __forceinline__ ushort f2bf_rne(float x) {
  unsigned int u = __float_as_uint(x);
  u += 0x7FFFu + ((u >> 16) & 1u);
  return (ushort)(u >> 16);
}

__device__ __forceinline__ float bf2f(ushort u) {
  unsigned int v = ((unsigned int)u) << 16;
  return __uint_as_float(v);
}

// async 16B global->LDS (wave-uniform LDS base + lane*16)
__device__ __forceinline__ void async_copy16(const void* g, void* l) {
  __builtin_amdgcn_global_load_lds(
      (const __attribute__((address_space(1))) unsigned int*)g,
      (__attribute__((address_space(3))) unsigned int*)l, 16, 0, 0);
}

// ---------------- fused init: zero nodeA + cnt, weight conversions ----------------
__global__ void k_init(float4* __restrict__ nodeA, int n4, int* __restrict__ cnt, int n,
                       const float* __restrict__ Wl, const float* __restrict__ Wx,
                       const float* __restrict__ Wls, const float* __restrict__ Wout,
                       ushort* __restrict__ Wlbf,
                       ushort* __restrict__ Wxhi, ushort* __restrict__ Wxlo,
                       ushort* __restrict__ Wlshi, ushort* __restrict__ Wlslo,
                       ushort* __restrict__ Wouthi, ushort* __restrict__ Woutlo) {
  int i = blockIdx.x * blockDim.x + threadIdx.x;
  if (i < n4) nodeA[i] = make_float4(0.f, 0.f, 0.f, 0.f);
  if (i < n) cnt[i] = 0;
  int idx = i;
  if (idx < 49152) {
    Wlbf[idx] = f2bf(Wl[idx]);
    return;
  }
  idx -= 49152;
  if (idx < 16384) {
    float x = Wx[idx];
    ushort h = f2bf(x);
    Wxhi[idx] = h; Wxlo[idx] = f2bf(x - bf2f(h));
    return;
  }
  idx -= 16384;
  if (idx < 49152) {
    float x = Wls[idx];
    ushort h = f2bf(x);
    Wlshi[idx] = h; Wlslo[idx] = f2bf(x - bf2f(h));
    return;
  }
  idx -= 49152;
  if (idx < 8192) {
    float x = Wout[idx];
    ushort h = f2bf(x);
    Wouthi[idx] = h; Woutlo[idx] = f2bf(x - bf2f(h));
  }
}

// ---------------- counting sort by dst: hist / parallel scan ----------------
__global__ void k_hist(const int* __restrict__ dst, int* __restrict__ cnt, int E) {
  int i = blockIdx.x * blockDim.x + threadIdx.x;
  if (i < E) atomicAdd(&cnt[dst[i]], 1);
}

// Level A: per-block (1024 elems) local exclusive scan + block total.
__global__ __launch_bounds__(1024) void k_scanA(const int* __restrict__ cnt,
                                                int* __restrict__ cur,
                                                int* __restrict__ bsum, int N) {
  __shared__ int wsum[16];
  const int tid = threadIdx.x;
  const int gid = blockIdx.x * 1024 + tid;
  const int lane = tid & 63, wv = tid >> 6;
  int v0 = (gid < N) ? cnt[gid] : 0;
  int v = v0;
#pragma unroll
  for (int off = 1; off < 64; off <<= 1) {
    int t = __shfl_up(v, off, 64);
    if (lane >= off) v += t;
  }
  if (lane == 63) wsum[wv] = v;
  __syncthreads();
  if (wv == 0 && lane < 16) {
    int t = wsum[lane];
#pragma unroll
    for (int off = 1; off < 16; off <<= 1) {
      int u2 = __shfl_up(t, off, 64);
      if (lane >= off) t += u2;
    }
    wsum[lane] = t;  // inclusive wave sums
  }
  __syncthreads();
  int excl = (wv > 0 ? wsum[wv - 1] : 0) + (v - v0);  // block-local exclusive
  if (gid < N) cur[gid] = excl;
  if (tid == 0) bsum[blockIdx.x] = wsum[15];           // block total
}

// ---------------- fused scatter + per-edge rbf + triplet angles ----------------
// No scanB kernel: each edge-block computes the (<=64-entry) block-offset prefix
// from bsum itself (one wave scan + barrier). For edge i:
// p = boffS[d>>10] + atomicAdd(cur[d]) is its sorted slot; the record
// {rbf[6], src, dst} is exactly 32B -> two aligned float4 stores (one stream,
// no partial-line amplification vs the old 24B+4B+4B triple-stream scatter).
__global__ __launch_bounds__(256) void k_scatter_feat_ang(
    const float* __restrict__ pos, const int* __restrict__ esrc,
    const int* __restrict__ edst, const float* __restrict__ freq,
    int* __restrict__ cur, const int* __restrict__ bsum, int nscan,
    float* __restrict__ epk,        // [E][8]: rbf[6], src bits, dst bits (sorted)
    int E, int EB,
    const int* __restrict__ ii, const int* __restrict__ jj, const int* __restrict__ kk,
    float* __restrict__ ang, int T) {
  if (blockIdx.x < (unsigned)EB) {
    __shared__ int boffS[64];
    {
      const int lane = threadIdx.x & 63;
      if (threadIdx.x < 64) {
        int v = (lane < nscan) ? bsum[lane] : 0;
        int v0 = v;
#pragma unroll
        for (int off = 1; off < 64; off <<= 1) {
          int t = __shfl_up(v, off, 64);
          if (lane >= off) v += t;
        }
        boffS[lane] = v - v0;  // exclusive prefix
      }
    }
    __syncthreads();
    int i = blockIdx.x * 256 + threadIdx.x;
    if (i >= E) return;
    const int s = esrc[i], d = edst[i];
    const int p = atomicAdd(&cur[d], 1) + boffS[d >> 10];
    float dx = pos[d * 3 + 0] - pos[s * 3 + 0];
    float dy = pos[d * 3 + 1] - pos[s * 3 + 1];
    float dz = pos[d * 3 + 2] - pos[s * 3 + 2];
    float dist = sqrtf(dx * dx + dy * dy + dz * dz);
    float dn = dist * 0.2f;
    float inv = __builtin_amdgcn_rcpf(dn);   // feeds bf16-precision path; rcp ok
    float dn2 = dn * dn;
    float dp = dn2 * dn2 * dn;  // dn^5
    float env = inv - 21.0f * dp + 35.0f * dp * dn - 15.0f * dp * dn2;
    float rb[NR];
#pragma unroll
    for (int r = 0; r < NR; ++r) rb[r] = env * __sinf(freq[r] * dn);
    float4 w0 = make_float4(rb[0], rb[1], rb[2], rb[3]);
    float4 w1 = make_float4(rb[4], rb[5], __int_as_float(s), __int_as_float(d));
    *(float4*)&epk[(size_t)p * 8] = w0;
    *(float4*)&epk[(size_t)p * 8 + 4] = w1;
  } else {
    int t = (blockIdx.x - EB) * 256 + threadIdx.x;
    if (t >= T) return;
    int i = ii[t], j = jj[t], k = kk[t];
    float pix = pos[i * 3], piy = pos[i * 3 + 1], piz = pos[i * 3 + 2];
    float vjx = pos[j * 3] - pix, vjy = pos[j * 3 + 1] - piy, vjz = pos[j * 3 + 2] - piz;
    float vkx = pos[k * 3] - pix, vky = pos[k * 3 + 1] - piy, vkz = pos[k * 3 + 2] - piz;
    float a = vjx * vkx + vjy * vky + vjz * vkz;
    float cx = vjy * vkz - vjz * vky;
    float cy = vjz * vkx - vjx * vkz;
    float cz = vjx * vky - vjy * vkx;
    float b = sqrtf(cx * cx + cy * cy + cz * cz);
    ang[t] = atan2f(b, a);   // direct output: keep libm accuracy
  }
}

// ---------------- x @ Wx^T -> bf16, 128-row tiles, 512 threads ----------------
__global__ __launch_bounds__(512, 4) void k_x_gemm(
    const float* __restrict__ A,      // [M][128] fp32
    const ushort* __restrict__ Bhi,   // [128][128]
    const ushort* __restrict__ Blo,
    ushort* __restrict__ C,           // [M][128] bf16
    int M) {
  __shared__ alignas(16) ushort Ah[128 * 32];
  __shared__ alignas(16) ushort Al[128 * 32];
  __shared__ alignas(16) ushort Bh[128 * 32];
  __shared__ alignas(16) ushort Bl[128 * 32];

  const int tid = threadIdx.x;
  const int m0 = blockIdx.x * 128;
  const int w = tid >> 6, lane = tid & 63;
  const int l15 = lane & 15, quad = lane >> 4;
  const int wm = (w >> 1) * 32;   // 4 row strips over 128
  const int wn = (w & 1) * 64;    // 2 col halves

  floatx4 acc[2][4];
#pragma unroll
  for (int i = 0; i < 2; ++i)
#pragma unroll
    for (int j = 0; j < 4; ++j) acc[i][j] = floatx4{0.f, 0.f, 0.f, 0.f};

  for (int c = 0; c < 4; ++c) {
    const int kb = c * 32;
    {
      int row = tid >> 2, g = tid & 3;   // 128 rows x 4 K-groups
      int m = m0 + row;
      float4 v0 = make_float4(0.f, 0.f, 0.f, 0.f), v1 = v0;
      if (m < M) {
        v0 = *(const float4*)&A[(size_t)m * 128 + kb + g * 8];
        v1 = *(const float4*)&A[(size_t)m * 128 + kb + g * 8 + 4];
      }
      float xs[8] = {v0.x, v0.y, v0.z, v0.w, v1.x, v1.y, v1.z, v1.w};
      short8 hi, lo;
#pragma unroll
      for (int j = 0; j < 8; ++j) {
        ushort h = f2bf_rne(xs[j]);
        hi[j] = (short)h;
        lo[j] = (short)f2bf_rne(xs[j] - bf2f(h));
      }
      int slot = row * 4 + (g ^ ((row >> 1) & 3));
      *(short8*)(Ah + slot * 8) = hi;
      *(short8*)(Al + slot * 8) = lo;
    }
    {
      // B: 128 rows x 32 K = 512 16B-units, 8 waves x 1 issue
      int s = w * 64 + lane;
      int brow = s >> 2, gp = s & 3;
      int gg = gp ^ ((brow >> 1) & 3);
      int lb = __builtin_amdgcn_readfirstlane(w * 64);
      async_copy16((const void*)(Bhi + (size_t)brow * 128 + kb + gg * 8), (void*)(Bh + lb * 8));
      async_copy16((const void*)(Blo + (size_t)brow * 128 + kb + gg * 8), (void*)(Bl + lb * 8));
    }
    __syncthreads();
    short8 ah[2], al[2], bh[4], blv[4];
#pragma unroll
    for (int i = 0; i < 2; ++i) {
      int m = wm + i * 16 + l15;
      int slot = m * 4 + (quad ^ ((m >> 1) & 3));
      ah[i] = *(const short8*)(Ah + slot * 8);
      al[i] = *(const short8*)(Al + slot * 8);
    }
#pragma unroll
    for (int j = 0; j < 4; ++j) {
      int n = wn + j * 16 + l15;
      int slot = n * 4 + (quad ^ ((n >> 1) & 3));
      bh[j] = *(const short8*)(Bh + slot * 8);
      blv[j] = *(const short8*)(Bl + slot * 8);
    }
#pragma unroll
    for (int i = 0; i < 2; ++i)
#pragma unroll
      for (int j = 0; j < 4; ++j) {
        acc[i][j] = __builtin_amdgcn_mfma_f32_16x16x32_bf16(ah[i], bh[j], acc[i][j], 0, 0, 0);
        acc[i][j] = __builtin_amdgcn_mfma_f32_16x16x32_bf16(ah[i], blv[j], acc[i][j], 0, 0, 0);
        acc[i][j] = __builtin_amdgcn_mfma_f32_16x16x32_bf16(al[i], bh[j], acc[i][j], 0, 0, 0);
      }
    __syncthreads();
  }

#pragma unroll
  for (int i = 0; i < 2; ++i)
#pragma unroll
    for (int r = 0; r < 4; ++r) {
      int m = m0 + wm + i * 16 + quad * 4 + r;
      if (m < M) {
#pragma unroll
        for (int j = 0; j < 4; ++j) {
          int n = wn + j * 16 + l15;
          C[(size_t)m * 128 + n] = f2bf_rne(acc[i][j][r]);
        }
      }
    }
}

// ---------------- fused node MLP: 3x (swish o Wls) + Wout, 512 threads ----------
__global__ __launch_bounds__(512, 4) void k_node_mlp(
    const float* __restrict__ nodeA,   // [M][128]
    const ushort* __restrict__ Wlshi,  // [3][128][128]
    const ushort* __restrict__ Wlslo,
    const ushort* __restrict__ Wouthi, // [64][128]
    const ushort* __restrict__ Woutlo,
    const float* __restrict__ bls,     // [3][128]
    float* __restrict__ P,             // [M][64]
    int M) {
  __shared__ alignas(16) ushort AactH[64 * 16 * 8];
  __shared__ alignas(16) ushort AactL[64 * 16 * 8];
  __shared__ alignas(16) ushort Bh[128 * 4 * 8];
  __shared__ alignas(16) ushort Bl[128 * 4 * 8];
  __shared__ float blsS[3 * 128];

  const int tid = threadIdx.x;
  const int m0 = blockIdx.x * 64;
  const int w = tid >> 6, lane = tid & 63;
  const int l15 = lane & 15, quad = lane >> 4;
  const int wm = (w >> 2) * 32;   // 2 row strips over 64
  const int wn = (w & 3) * 32;    // 4 col strips over 128

  for (int i = tid; i < 3 * 128; i += 512) blsS[i] = bls[i];

  floatx4 acc[2][2];

  for (int p = 0; p < 3; ++p) {
    const ushort* Bhg = Wlshi + p * 128 * 128;
    const ushort* Blg = Wlslo + p * 128 * 128;
#pragma unroll
    for (int i = 0; i < 2; ++i)
#pragma unroll
      for (int j = 0; j < 2; ++j) acc[i][j] = floatx4{0.f, 0.f, 0.f, 0.f};

    for (int c = 0; c < 4; ++c) {
      const int kb = c * 32;
      {
        // B: 128 rows x 32 K = 512 units, 8 waves x 1 issue
        int s = w * 64 + lane;
        int brow = s >> 2, gp = s & 3;
        int gg = gp ^ ((brow >> 1) & 3);
        int lb = __builtin_amdgcn_readfirstlane(w * 64);
        async_copy16((const void*)(Bhg + (size_t)brow * 128 + kb + gg * 8), (void*)(Bh + lb * 8));
        async_copy16((const void*)(Blg + (size_t)brow * 128 + kb + gg * 8), (void*)(Bl + lb * 8));
      }
      __syncthreads();
      short8 ah[2], al[2];
      if (p == 0) {
#pragma unroll
        for (int i = 0; i < 2; ++i) {
          int m = m0 + wm + i * 16 + l15;
          float4 v0 = make_float4(0.f, 0.f, 0.f, 0.f), v1 = v0;
          if (m < M) {
            v0 = *(const float4*)&nodeA[(size_t)m * 128 + kb + quad * 8];
            v1 = *(const float4*)&nodeA[(size_t)m * 128 + kb + quad * 8 + 4];
          }
          float xs[8] = {v0.x, v0.y, v0.z, v0.w, v1.x, v1.y, v1.z, v1.w};
#pragma unroll
          for (int j = 0; j < 8; ++j) {
            ushort hh = f2bf_rne(xs[j]);
            ah[i][j] = (short)hh;
            al[i][j] = (short)f2bf_rne(xs[j] - bf2f(hh));
          }
        }
      } else {
#pragma unroll
        for (int i = 0; i < 2; ++i) {
          int arow = wm + i * 16 + l15;
          int g16 = c * 4 + quad;
          int slot = arow * 16 + (g16 ^ (arow & 15));
          ah[i] = *(const short8*)(AactH + slot * 8);
          al[i] = *(const short8*)(AactL + slot * 8);
        }
      }
      short8 bh[2], blv[2];
#pragma unroll
      for (int j = 0; j < 2; ++j) {
        int n = wn + j * 16 + l15;
        int slot = n * 4 + (quad ^ ((n >> 1) & 3));
        bh[j] = *(const short8*)(Bh + slot * 8);
        blv[j] = *(const short8*)(Bl + slot * 8);
      }
#pragma unroll
      for (int i = 0; i < 2; ++i)
#pragma unroll
        for (int j = 0; j < 2; ++j) {
          acc[i][j] = __builtin_amdgcn_mfma_f32_16x16x32_bf16(ah[i], bh[j], acc[i][j], 0, 0, 0);
          acc[i][j] = __builtin_amdgcn_mfma_f32_16x16x32_bf16(ah[i], blv[j], acc[i][j], 0, 0, 0);
          acc[i][j] = __builtin_amdgcn_mfma_f32_16x16x32_bf16(al[i], bh[j], acc[i][j], 0, 0, 0);
        }
      __syncthreads();
    }
#pragma unroll
    for (int i = 0; i < 2; ++i)
#pragma unroll
      for (int r = 0; r < 4; ++r) {
        int row = wm + i * 16 + quad * 4 + r;
#pragma unroll
        for (int j = 0; j < 2; ++j) {
          int col = wn + j * 16 + l15;
          float z = acc[i][j][r] + blsS[p * 128 + col];
          z = swishf(z);
          ushort hh = f2bf_rne(z);
          int slot = row * 16 + ((col >> 3) ^ (row & 15));
          AactH[slot * 8 + (col & 7)] = hh;
          AactL[slot * 8 + (col & 7)] = f2bf_rne(z - bf2f(hh));
        }
      }
    __syncthreads();
  }

  const int wn3 = (w & 3) * 16;   // 4 col strips of 16 over 64
#pragma unroll
  for (int i = 0; i < 2; ++i) acc[i][0] = floatx4{0.f, 0.f, 0.f, 0.f};

  for (int c = 0; c < 4; ++c) {
    const int kb = c * 32;
    if (w < 4) {
      // Wout: 64 rows x 32 K = 256 units, waves 0-3 x 1 issue
      int s = w * 64 + lane;
      int brow = s >> 2, gp = s & 3;
      int gg = gp ^ ((brow >> 1) & 3);
      int lb = __builtin_amdgcn_readfirstlane(w * 64);
      async_copy16((const void*)(Wouthi + (size_t)brow * 128 + kb + gg * 8), (void*)(Bh + lb * 8));
      async_copy16((const void*)(Woutlo + (size_t)brow * 128 + kb + gg * 8), (void*)(Bl + lb * 8));
    }
    __syncthreads();
    short8 ah[2], al[2], bh, blv;
#pragma unroll
    for (int i = 0; i < 2; ++i) {
      int arow = wm + i * 16 + l15;
      int g16 = c * 4 + quad;
      int slot = arow * 16 + (g16 ^ (arow & 15));
      ah[i] = *(const short8*)(AactH + slot * 8);
      al[i] = *(const short8*)(AactL + slot * 8);
    }
    {
      int n = wn3 + l15;
      int slot = n * 4 + (quad ^ ((n >> 1) & 3));
      bh = *(const short8*)(Bh + slot * 8);
      blv = *(const short8*)(Bl + slot * 8);
    }
#pragma unroll
    for (int i = 0; i < 2; ++i) {
      acc[i][0] = __builtin_amdgcn_mfma_f32_16x16x32_bf16(ah[i], bh, acc[i][0], 0, 0, 0);
      acc[i][0] = __builtin_amdgcn_mfma_f32_16x16x32_bf16(ah[i], blv, acc[i][0], 0, 0, 0);
      acc[i][0] = __builtin_amdgcn_mfma_f32_16x16x32_bf16(al[i], bh, acc[i][0], 0, 0, 0);
    }
    __syncthreads();
  }
#pragma unroll
  for (int i = 0; i < 2; ++i)
#pragma unroll
    for (int r = 0; r < 4; ++r) {
      int m = m0 + wm + i * 16 + quad * 4 + r;
      if (m < M) {
        int n = wn3 + l15;
        P[(size_t)m * NOUT + n] = acc[i][0][r];
      }
    }
}

// ---------------- MFMA fused edge block: 128-edge tile, 8 waves ----------------
// K=384 in 3 chunks of 128 (c0=h[dst], c1=h[src], c2=rbf_h in-place VALU).
// Full-width single-pass epilogue (redS[128][130] aliased over As|Bs).
// Round-7 form (proven 103.6-105.7us). Prologue now reads the packed 32B
// edge record (rbf[6], src, dst) — one coalesced 4KB stream per tile.
// launch_bounds note: 2nd arg is waves/SIMD; (512,4) => VGPR cap 128. (512,8)
// capped at 64 and spilled ~700MB/dispatch (round-3 regression).
__global__ __launch_bounds__(512, 4) void k_edge_mfma(
    const ushort* __restrict__ hbf,    // [N][128] bf16
    const ushort* __restrict__ Wlbf,   // [128][384] bf16
    const float* __restrict__ bl,      // [128]
    const float* __restrict__ epk,     // [E][8]: rbf[6], src bits, dst bits (sorted)
    const float* __restrict__ Wr,      // [128][6]
    const float* __restrict__ br,      // [128]
    const float* __restrict__ Wrbf,    // [128][6]
    float* __restrict__ node,          // [N,128]
    int E, int nb, int perXcd) {
  // As[128 rows][16 units] | Bs[128 rows][16 units] = 32768 ushorts;
  // epilogue alias: redS[128][130] f32 = 33280 ushorts (stride 130 -> 2-way banks)
  __shared__ alignas(16) ushort ABs[33280];
  __shared__ float rbfS[128][6];
  __shared__ int dstS[128];
  __shared__ int srcS[128];

  const int bp = blockIdx.x;
  const int lb = (bp & 7) * perXcd + (bp >> 3);
  if (lb >= nb) return;

  ushort* As = ABs;                 // [128][128] K-major, 16B-unit swizzled (&15)
  ushort* Bs = ABs + 128 * 16 * 8;  // [128 N-rows][128 K]

  const int tid = threadIdx.x;
  const int e0 = lb * 128;

  if (tid < 128) {
    int e = min(e0 + tid, E - 1);
    const float* rec = epk + (size_t)e * 8;
    float4 r0 = *(const float4*)rec;
    float4 r1 = *(const float4*)(rec + 4);
    bool ok = (e0 + tid < E);
    rbfS[tid][0] = ok ? r0.x : 0.f;
    rbfS[tid][1] = ok ? r0.y : 0.f;
    rbfS[tid][2] = ok ? r0.z : 0.f;
    rbfS[tid][3] = ok ? r0.w : 0.f;
    rbfS[tid][4] = ok ? r1.x : 0.f;
    rbfS[tid][5] = ok ? r1.y : 0.f;
    srcS[tid] = __float_as_int(r1.z);
    dstS[tid] = __float_as_int(r1.w);
  }
  __syncthreads();

  const int w = tid >> 6;           // 8 waves
  const int lane = tid & 63;
  const int l15 = lane & 15, quad = lane >> 4;
  const int wm = (w >> 1) * 32;     // edge strip: 0/32/64/96
  const int wn = (w & 1) * 64;      // col strip: 0 or 64

  floatx4 acc[2][4];
#pragma unroll
  for (int i = 0; i < 2; ++i)
#pragma unroll
    for (int j = 0; j < 4; ++j) acc[i][j] = floatx4{0.f, 0.f, 0.f, 0.f};

  for (int c = 0; c < 3; ++c) {
    // B tile: 128 rows x 128 K = 2048 16B-units, 8 waves x 4 issues
#pragma unroll
    for (int i = 0; i < 4; ++i) {
      int u = w * 256 + i * 64 + lane;
      int nrow = u >> 4, gp = u & 15;
      int g = gp ^ (nrow & 15);
      const ushort* gsrc = Wlbf + (size_t)nrow * 384 + c * 128 + g * 8;
      int lbo = __builtin_amdgcn_readfirstlane(w * 256 + i * 64);
      async_copy16((const void*)gsrc, (void*)(Bs + lbo * 8));
    }
    if (c < 2) {
      // A tile = full h rows gathered via dst (c=0) / src (c=1): 2048 units
      const int* rowS = (c == 0) ? dstS : srcS;
#pragma unroll
      for (int i = 0; i < 4; ++i) {
        int u = w * 256 + i * 64 + lane;
        int nrow = u >> 4;
        int g = (u & 15) ^ (nrow & 15);
        int row = rowS[nrow];
        const ushort* gsrc = hbf + (size_t)row * H + g * 8;
        int lbo = __builtin_amdgcn_readfirstlane(w * 256 + i * 64);
        async_copy16((const void*)gsrc, (void*)(As + lbo * 8));
      }
    } else {
      // A tile = rbf_h = swish(rbf @ Wr^T + br), all 128 cols in one phase.
      // Thread owns col (tid&127), rows (tid>>7)*32..+32. rbfS reads broadcast.
      const int colL = tid & 127;
      float w0 = Wr[colL * NR + 0], w1 = Wr[colL * NR + 1], w2 = Wr[colL * NR + 2];
      float w3 = Wr[colL * NR + 3], w4 = Wr[colL * NR + 4], w5 = Wr[colL * NR + 5];
      float bv = br[colL];
      const int r0 = (tid >> 7) * 32;
#pragma unroll
      for (int r = 0; r < 32; ++r) {
        int m = r0 + r;
        const float2* rp = (const float2*)&rbfS[m][0];
        float2 q0 = rp[0], q1 = rp[1], q2 = rp[2];
        float z = bv + q0.x * w0 + q0.y * w1 + q1.x * w2 + q1.y * w3 + q2.x * w4 + q2.y * w5;
        ushort hv = f2bf_rne(swishf(z));
        As[(m * 16 + ((colL >> 3) ^ (m & 15))) * 8 + (colL & 7)] = hv;
      }
    }
    __syncthreads();
#pragma unroll
    for (int s = 0; s < 4; ++s) {
      const int gg = s * 4 + quad;
      short8 af[2], bfr[4];
#pragma unroll
      for (int i = 0; i < 2; ++i) {
        int m = wm + i * 16 + l15;
        af[i] = *(const short8*)(As + (m * 16 + (gg ^ (m & 15))) * 8);
      }
#pragma unroll
      for (int j = 0; j < 4; ++j) {
        int n = wn + j * 16 + l15;
        bfr[j] = *(const short8*)(Bs + (n * 16 + (gg ^ (n & 15))) * 8);
      }
#pragma unroll
      for (int i = 0; i < 2; ++i)
#pragma unroll
        for (int j = 0; j < 4; ++j)
          acc[i][j] = __builtin_amdgcn_mfma_f32_16x16x32_bf16(af[i], bfr[j], acc[i][j], 0, 0, 0);
    }
    __syncthreads();   // also fences As|Bs reads before redS overwrite (c==2)
  }

  // ---- epilogue: t = swish(z+bl) * (rbf . Wrbf[n]); single full-width pass ----
  float* redS = (float*)ABs;   // [128][130] f32 (stride 130 => 2-way banks)
  float wt[4][NR], blv[4];
#pragma unroll
  for (int j = 0; j < 4; ++j) {
    int n = wn + j * 16 + l15;
    blv[j] = bl[n];
#pragma unroll
    for (int r = 0; r < NR; ++r) wt[j][r] = Wrbf[n * NR + r];
  }

  // all 8 waves write their 32x64 quadrant (rows wm.., cols wn..)
#pragma unroll
  for (int i = 0; i < 2; ++i)
#pragma unroll
    for (int r = 0; r < 4; ++r) {
      int mg = wm + i * 16 + quad * 4 + r;
      float rb[NR];
#pragma unroll
      for (int q = 0; q < NR; ++q) rb[q] = rbfS[mg][q];
#pragma unroll
      for (int j = 0; j < 4; ++j) {
        float z = acc[i][j][r] + blv[j];
        float ev = swishf(z);
        float wv = 0.f;
#pragma unroll
        for (int q = 0; q < NR; ++q) wv += rb[q] * wt[j][q];
        redS[mg * 130 + wn + j * 16 + l15] = ev * wv;  // zero when e>=E (rb==0)
      }
    }
  __syncthreads();

  // reduce: 512 threads, col = tid&127, 4 row-chunks of 32; coalesced atomics
  {
    int cc = tid & 127, chunk = tid >> 7;
    int ml0 = chunk * 32;
    float s = 0.f;
    int prev = dstS[ml0];
#pragma unroll
    for (int ml = ml0; ml < ml0 + 32; ++ml) {
      int d = dstS[ml];
      float v = redS[ml * 130 + cc];
      if (d != prev) {
        atomicAdd(&node[(size_t)prev * H + cc], s);
        s = 0.f;
        prev = d;
      }
      s += v;
    }
    atomicAdd(&node[(size_t)prev * H + cc], s);
  }
}

extern "C" void kernel_launch(void* const* d_in, const int* in_sizes, int n_in,
                              void* d_out, int out_size, void* d_ws, size_t ws_size,
                              hipStream_t stream) {
  const float* x    = (const float*)d_in[0];
  const float* pos  = (const float*)d_in[1];
  const float* freq = (const float*)d_in[2];
  const float* Wx   = (const float*)d_in[3];
  const float* Wr   = (const float*)d_in[4];
  const float* br   = (const float*)d_in[5];
  const float* Wl   = (const float*)d_in[6];
  const float* bl   = (const float*)d_in[7];
  const float* Wrbf = (const float*)d_in[8];
  const float* Wls  = (const float*)d_in[9];
  const float* bls  = (const float*)d_in[10];
  const float* Wout = (const float*)d_in[11];
  const int* esrc = (const int*)d_in[12];
  const int* edst = (const int*)d_in[13];
  const int* ii   = (const int*)d_in[14];
  const int* jjv  = (const int*)d_in[15];
  const int* kkv  = (const int*)d_in[16];

  const int N = in_sizes[0] / H;
  const int E = in_sizes[12];
  const int T = in_sizes[14];

  float* out   = (float*)d_out;
  float* P     = out;                       // [N,64]
  float* angle = out + (size_t)N * NOUT;    // [T]

  float* ws = (float*)d_ws;
  float* epk   = ws; ws += (size_t)E * 8;   // packed edge records (sorted)
  float* nodeA = ws; ws += (size_t)N * H;
  ushort* u = (ushort*)ws;
  ushort* hbf    = u; u += (size_t)N * H;
  ushort* Wlbf   = u; u += 3 * H * H;
  ushort* Wxhi   = u; u += H * H;
  ushort* Wxlo   = u; u += H * H;
  ushort* Wlshi  = u; u += 3 * H * H;
  ushort* Wlslo  = u; u += 3 * H * H;
  ushort* Wouthi = u; u += NOUT * H;
  ushort* Woutlo = u; u += NOUT * H;
  int* ip = (int*)u;
  int* cnt   = ip; ip += N;
  int* cur   = ip; ip += N;
  int* bsum  = ip; ip += 256;

  // fused zeros + weight prep
  {
    int n4 = N * H / 4;
    k_init<<<(n4 + 255) / 256, 256, 0, stream>>>((float4*)nodeA, n4, cnt, N,
                                                 Wl, Wx, Wls, Wout, Wlbf,
                                                 Wxhi, Wxlo, Wlshi, Wlslo, Wouthi, Woutlo);
  }

  // counting sort of edges by dst: hist + per-block scan (block offsets folded
  // into the scatter kernel's LDS prefix)
  const int nscan = (N + 1023) / 1024;
  k_hist<<<(E + 255) / 256, 256, 0, stream>>>(edst, cnt, E);
  k_scanA<<<nscan, 1024, 0, stream>>>(cnt, cur, bsum, N);

  // fused scatter + per-edge rbf (packed 32B record at sorted slot) + angles
  {
    int EB = (E + 255) / 256;
    int TB = (T + 255) / 256;
    k_scatter_feat_ang<<<EB + TB, 256, 0, stream>>>(pos, esrc, edst, freq, cur,
                                                    bsum, nscan, epk, E, EB,
                                                    ii, jjv, kkv, angle, T);
  }

  // h = x @ Wx^T -> bf16 (128-row tiles, 512 threads)
  k_x_gemm<<<(N + 127) / 128, 512, 0, stream>>>(x, Wxhi, Wxlo, hbf, N);

  // fused MFMA edge block (128-edge tiles, XCD swizzle) -> segmented sum into nodeA
  {
    int nb = (E + 127) / 128;
    int perXcd = (nb + 7) / 8;
    int grid = perXcd * 8;
    k_edge_mfma<<<grid, 512, 0, stream>>>(hbf, Wlbf, bl, epk, Wr, br, Wrbf,
                                          nodeA, E, nb, perXcd);
  }

  // fused node MLP (512 threads, 2x4 wave quadrants)
  k_node_mlp<<<(N + 63) / 64, 512, 0, stream>>>(nodeA, Wlshi, Wlslo, Wouthi, Woutlo,
                                                bls, P, N);
}